// Round 2
// baseline (10790.858 us; speedup 1.0000x reference)
//
#include <hip/hip_runtime.h>
#include <hip/hip_bf16.h>

// Problem dims
#define B_   512
#define WIN_ 128
#define D_   256
#define H_   512
#define O_   64
#define P_   64
#define K2H  1024   // 2H (q = [h|c])
#define KG   832    // gates GEMM K = O(64) + D(256) + H(512)
#define NQY  320    // fused Wq(256) + y(64) GEMM N
#define NBLK 256    // persistent decode blocks (1 per CU)

typedef __attribute__((ext_vector_type(8))) short bf16x8;
typedef __attribute__((ext_vector_type(4))) float f32x4;
using bf16 = __hip_bfloat16;

__device__ __forceinline__ float fast_tanh(float x){
    float e = __expf(2.f * x);
    return 1.f - __fdividef(2.f, e + 1.f);
}
__device__ __forceinline__ float fast_sig(float x){
    return __fdividef(1.f, 1.f + __expf(-x));
}
__device__ __forceinline__ float b_lo(unsigned int u){ return __uint_as_float(u << 16); }
__device__ __forceinline__ float b_hi(unsigned int u){ return __uint_as_float(u & 0xffff0000u); }
__device__ __forceinline__ unsigned int pack2(float a, float b){
    unsigned short sa = __builtin_bit_cast(unsigned short, __float2bfloat16(a));
    unsigned short sb = __builtin_bit_cast(unsigned short, __float2bfloat16(b));
    return (unsigned int)sa | ((unsigned int)sb << 16);
}

// monotonic-counter grid barrier (256 co-resident blocks, device scope)
__device__ __forceinline__ void grid_bar(unsigned int* cnt, unsigned int target)
{
    __syncthreads();
    if (threadIdx.x == 0) {
        __threadfence();  // release: flush this XCD's dirty L2 to L3
        __hip_atomic_fetch_add(cnt, 1u, __ATOMIC_RELAXED, __HIP_MEMORY_SCOPE_AGENT);
        int guard = 0;
        while (__hip_atomic_load(cnt, __ATOMIC_RELAXED, __HIP_MEMORY_SCOPE_AGENT) < target) {
            __builtin_amdgcn_s_sleep(2);
            if (++guard > (1 << 24)) break;   // safety bailout, never hit in correct runs
        }
        __threadfence();  // acquire: invalidate local caches
    }
    __syncthreads();
}

// ---------------- prep: dtype conversions + weight packing ----------------
__global__ void k_prep(const float* __restrict__ x, const float* __restrict__ W,
                       const float* __restrict__ U, const float* __restrict__ W_ih,
                       const float* __restrict__ W_hh, const float* __restrict__ b_ih,
                       const float* __restrict__ b_hh, const float* __restrict__ Wd,
                       bf16* __restrict__ x_bf, bf16* __restrict__ Wcomb,
                       bf16* __restrict__ Wqy, bf16* __restrict__ U_bf,
                       float* __restrict__ bsum, bf16* __restrict__ A0,
                       unsigned int* __restrict__ bar_cnt)
{
    if (blockIdx.x == 0 && threadIdx.x == 0) *bar_cnt = 0u;   // reset barrier each launch
    const long NX  = (long)B_ * WIN_ * D_;
    const long NWC = (long)2048 * KG;
    const long NWQ = (long)NQY * K2H;
    const long NU  = (long)D_ * D_;
    const long NB  = 2048;
    const long NAY = (long)B_ * O_;
    const long total = NX + NWC + NWQ + NU + NB + NAY;
    for (long i = (long)blockIdx.x * blockDim.x + threadIdx.x; i < total;
         i += (long)gridDim.x * blockDim.x) {
        long j = i;
        if (j < NX) { x_bf[j] = __float2bfloat16(x[j]); continue; }
        j -= NX;
        if (j < NWC) {
            long n = j / KG, k = j % KG;
            float v = (k < 320) ? W_ih[n * 320 + k] : W_hh[n * 512 + (k - 320)];
            Wcomb[j] = __float2bfloat16(v); continue;
        }
        j -= NWC;
        if (j < NWQ) {
            long n = j / K2H, k = j % K2H;
            float v;
            if (n < 256) v = W[n * K2H + k];
            else { long o = n - 256; v = (k < 512) ? Wd[o * 512 + k] : 0.f; }
            Wqy[j] = __float2bfloat16(v); continue;
        }
        j -= NWQ;
        if (j < NU) { U_bf[j] = __float2bfloat16(U[j]); continue; }
        j -= NU;
        if (j < NB) { bsum[j] = b_ih[j] + b_hh[j]; continue; }
        j -= NB;
        { long b = j / O_, o = j % O_; A0[b * KG + o] = __float2bfloat16(0.f); }
    }
}

// ---------------- init: h0 = tanh(x_last@Ws^T+bs), c0 = sig(x_last@Wc^T+bc) ----
__global__ void __launch_bounds__(256) k_init(const float* __restrict__ x,
                       const float* __restrict__ Ws, const float* __restrict__ bs,
                       const float* __restrict__ Wc, const float* __restrict__ bc,
                       bf16* __restrict__ q_buf, bf16* __restrict__ A0,
                       float* __restrict__ c_f32)
{
    __shared__ __align__(16) float xl[D_];
    int b = blockIdx.x >> 1;
    int j = (blockIdx.x & 1) * 256 + threadIdx.x;
    xl[threadIdx.x] = x[(long)b * (WIN_ * D_) + 127 * D_ + threadIdx.x];
    __syncthreads();
    float hv = bs[j], cv = bc[j];
    const float* wsr = Ws + (long)j * D_;
    const float* wcr = Wc + (long)j * D_;
    #pragma unroll 4
    for (int k = 0; k < D_; k += 4) {
        float4 xa = *(const float4*)&xl[k];
        float4 wa = *(const float4*)&wsr[k];
        float4 wb = *(const float4*)&wcr[k];
        hv += xa.x*wa.x + xa.y*wa.y + xa.z*wa.z + xa.w*wa.w;
        cv += xa.x*wb.x + xa.y*wb.y + xa.z*wb.z + xa.w*wb.w;
    }
    hv = fast_tanh(hv); cv = fast_sig(cv);
    bf16 hb = __float2bfloat16(hv);
    q_buf[(long)b * K2H + j]       = hb;
    q_buf[(long)b * K2H + 512 + j] = __float2bfloat16(cv);
    A0[(long)b * KG + 320 + j]     = hb;
    c_f32[(long)b * H_ + j]        = cv;
}

// ---------------- Uk[b] = U @ x[b]^T  (x-tile staged in LDS) ----------------
// Uk layout: [b][v(256)][w(128)], bf16
__global__ void __launch_bounds__(256) k_uk(const bf16* __restrict__ U_bf,
                    const bf16* __restrict__ x_bf, bf16* __restrict__ Uk)
{
    __shared__ __align__(16) short xs[64][264];   // +8 pad: stride 33 granules -> balanced banks
    int b  = blockIdx.y;
    int v0 = (blockIdx.x >> 1) * 64;
    int w0 = (blockIdx.x & 1) * 64;
    // stage x rows w0..w0+63 (32 KB) once per block
    {
        const short* xg = (const short*)x_bf + (long)b * (WIN_ * D_) + (long)w0 * D_;
        int row = threadIdx.x >> 2, cc = (threadIdx.x & 3) * 64;
        #pragma unroll
        for (int i = 0; i < 8; ++i)
            *(bf16x8*)(&xs[row][cc + i * 8]) = *(const bf16x8*)(xg + (long)row * D_ + cc + i * 8);
    }
    __syncthreads();
    int lane = threadIdx.x & 63;
    int wave = threadIdx.x >> 6;
    int r  = lane & 15;
    int ko = (lane >> 4) * 8;
    const short* Up = (const short*)U_bf + (long)(v0 + wave * 16 + r) * D_;
    f32x4 acc[4] = {};
    #pragma unroll 2
    for (int k0 = 0; k0 < D_; k0 += 32) {
        bf16x8 a = *(const bf16x8*)(Up + k0 + ko);
        #pragma unroll
        for (int f = 0; f < 4; ++f) {
            bf16x8 bb = *(const bf16x8*)(&xs[f * 16 + r][k0 + ko]);
            acc[f] = __builtin_amdgcn_mfma_f32_16x16x32_bf16(a, bb, acc[f], 0, 0, 0);
        }
    }
    bf16* up = Uk + (long)b * (D_ * WIN_);
    int vbase = v0 + wave * 16 + (lane >> 4) * 4;
    #pragma unroll
    for (int f = 0; f < 4; ++f) {
        int w = w0 + f * 16 + r;
        #pragma unroll
        for (int j = 0; j < 4; ++j)
            up[(long)(vbase + j) * WIN_ + w] = __float2bfloat16(acc[f][j]);
    }
}

// ---------------- persistent decode: 64 steps, 3 phases + 3 grid barriers ----
__global__ void __launch_bounds__(256) k_decode(
    const bf16* __restrict__ x_bf, const bf16* __restrict__ Uk,
    const bf16* __restrict__ Wqy, const bf16* __restrict__ Wcomb,
    const float* __restrict__ V, const float* __restrict__ bd,
    const float* __restrict__ bsum,
    bf16* __restrict__ q_buf, bf16* __restrict__ A0, bf16* __restrict__ A1,
    float* __restrict__ Wq, float* __restrict__ c_f32,
    float* __restrict__ out_y, float* __restrict__ out_w,
    unsigned int* __restrict__ bar_cnt)
{
    const int tid  = threadIdx.x;
    const int bid  = blockIdx.x;
    const int gid  = bid * 4 + (tid >> 6);
    const int lane = tid & 63;
    const int r    = lane & 15;
    const int ko   = (lane >> 4) * 8;
    const int rj   = (lane >> 4) * 4;

    __shared__ float v_s[D_];
    __shared__ float wq_s[D_];
    __shared__ float part[4][WIN_];
    __shared__ float att_s[WIN_];
    __shared__ float cpart[2][D_];
    __shared__ float redw[4];

    v_s[tid] = V[tid];

    const short* qp   = (const short*)q_buf;
    const short* wqyp = (const short*)Wqy;
    const short* wcp  = (const short*)Wcomb;

    unsigned int bar = 0;

    for (int s = 0; s < P_; ++s) {
        bf16* Acur  = (s & 1) ? A1 : A0;
        bf16* Anext = (s & 1) ? A0 : A1;

        // ---------- phase A : fused Wq + y GEMM (640 wave-tiles 16x16xK1024) ----------
        {
            int t = gid;
            if (t < 640) {
                int m0 = (t / 20) * 16;
                int n0 = (t % 20) * 16;
                f32x4 acc = {};
                #pragma unroll 4
                for (int k0 = 0; k0 < K2H; k0 += 32) {
                    bf16x8 a  = *(const bf16x8*)(qp   + (long)(m0 + r) * K2H + k0 + ko);
                    bf16x8 bb = *(const bf16x8*)(wqyp + (long)(n0 + r) * K2H + k0 + ko);
                    acc = __builtin_amdgcn_mfma_f32_16x16x32_bf16(a, bb, acc, 0, 0, 0);
                }
                int n = n0 + r;
                if (n0 < D_) {                      // Wq tile (wave-uniform branch)
                    #pragma unroll
                    for (int j = 0; j < 4; ++j)
                        Wq[(long)(m0 + rj + j) * D_ + n] = acc[j];
                } else if (s > 0) {                 // y tile
                    int o = n - D_;
                    float bo = bd[o];
                    #pragma unroll
                    for (int j = 0; j < 4; ++j) {
                        int b = m0 + rj + j;
                        float val = acc[j] + bo;
                        out_y[((long)b * P_ + (s - 1)) * O_ + o] = val;
                        Acur[(long)b * KG + o] = __float2bfloat16(val);
                    }
                }
            }
            ++bar; grid_bar(bar_cnt, NBLK * bar);
        }

        // ---------- phase B : attention, 2 batches per block ----------
        for (int half = 0; half < 2; ++half) {
            int b = bid * 2 + half;
            wq_s[tid] = Wq[(long)b * D_ + tid];
            __syncthreads();
            {   // score partials: thread = (w-pair, v-quarter)
                int w2 = tid & 63, vq = tid >> 6;
                const unsigned int* ukp =
                    (const unsigned int*)(Uk + (long)b * (D_ * WIN_) + (long)vq * 64 * WIN_) + w2;
                float sc0 = 0.f, sc1 = 0.f;
                #pragma unroll 8
                for (int i = 0; i < 64; ++i) {
                    unsigned int u = ukp[(long)i * 64];
                    int v = vq * 64 + i;
                    float wqv = wq_s[v], vv = v_s[v];
                    sc0 += vv * fast_tanh(wqv + b_lo(u));
                    sc1 += vv * fast_tanh(wqv + b_hi(u));
                }
                part[vq][w2 * 2]     = sc0;
                part[vq][w2 * 2 + 1] = sc1;
            }
            __syncthreads();
            float e = 0.f, scw = 0.f;
            if (tid < WIN_) {
                scw = part[0][tid] + part[1][tid] + part[2][tid] + part[3][tid];
                float m = scw;
                #pragma unroll
                for (int off = 32; off > 0; off >>= 1) m = fmaxf(m, __shfl_xor(m, off));
                if (lane == 0) redw[tid >> 6] = m;
            }
            __syncthreads();
            if (tid < WIN_) {
                float m = fmaxf(redw[0], redw[1]);
                e = __expf(scw - m);
                float l = e;
                #pragma unroll
                for (int off = 32; off > 0; off >>= 1) l += __shfl_xor(l, off);
                if (lane == 0) redw[2 + (tid >> 6)] = l;
            }
            __syncthreads();
            if (tid < WIN_) {
                float l = redw[2] + redw[3];
                float a = __fdividef(e, l);
                att_s[tid] = a;
                out_w[((long)b * P_ + s) * WIN_ + tid] = a;
            }
            __syncthreads();
            {   // ctx: thread = (d-pair, w-half)
                int d2 = tid & 127, wh = tid >> 7;
                const unsigned int* xp =
                    (const unsigned int*)(x_bf + (long)b * (WIN_ * D_) + (long)wh * 64 * D_) + d2;
                float c0 = 0.f, c1 = 0.f;
                #pragma unroll 8
                for (int i = 0; i < 64; ++i) {
                    unsigned int u = xp[(long)i * 128];
                    float a = att_s[wh * 64 + i];
                    c0 += a * b_lo(u);
                    c1 += a * b_hi(u);
                }
                cpart[wh][d2 * 2]     = c0;
                cpart[wh][d2 * 2 + 1] = c1;
            }
            __syncthreads();
            if (tid < 128) {
                int d = tid * 2;
                float f0 = cpart[0][d] + cpart[1][d];
                float f1 = cpart[0][d + 1] + cpart[1][d + 1];
                *(unsigned int*)(Acur + (long)b * KG + O_ + d) = pack2(f0, f1);
            }
            __syncthreads();
        }
        ++bar; grid_bar(bar_cnt, NBLK * bar);

        // ---------- phase C : gates GEMM + lane-local LSTM (1024 wave-tasks) ----------
        {
            int t = gid;
            int m0 = (t >> 5) * 16;
            int j0 = (t & 31) * 16;
            f32x4 acc[4] = {};
            const short* ap = (const short*)Acur;
            long arow = (long)(m0 + r) * KG;
            #pragma unroll 2
            for (int k0 = 0; k0 < KG; k0 += 32) {
                bf16x8 a = *(const bf16x8*)(ap + arow + k0 + ko);
                #pragma unroll
                for (int g = 0; g < 4; ++g) {
                    bf16x8 bb = *(const bf16x8*)(wcp + (long)(g * H_ + j0 + r) * KG + k0 + ko);
                    acc[g] = __builtin_amdgcn_mfma_f32_16x16x32_bf16(a, bb, acc[g], 0, 0, 0);
                }
            }
            int jj = j0 + r;
            float bi = bsum[jj], bff = bsum[H_ + jj], bg = bsum[2*H_ + jj], bo = bsum[3*H_ + jj];
            #pragma unroll
            for (int j = 0; j < 4; ++j) {
                int b = m0 + rj + j;
                float iv = acc[0][j] + bi;
                float fv = acc[1][j] + bff;
                float gv = acc[2][j] + bg;
                float ov = acc[3][j] + bo;
                float c_old = c_f32[(long)b * H_ + jj];
                float cn = fast_sig(fv) * c_old + fast_sig(iv) * fast_tanh(gv);
                float hn = fast_sig(ov) * fast_tanh(cn);
                c_f32[(long)b * H_ + jj] = cn;
                bf16 hb = __float2bfloat16(hn);
                Anext[(long)b * KG + 320 + jj]  = hb;
                q_buf[(long)b * K2H + jj]       = hb;
                q_buf[(long)b * K2H + H_ + jj]  = __float2bfloat16(cn);
            }
            ++bar; grid_bar(bar_cnt, NBLK * bar);
        }
    }

    // ---------- final y (row 63) from h_64 ----------
    {
        int t = gid;
        if (t < 128) {
            int m0 = (t >> 2) * 16;
            int n0 = D_ + (t & 3) * 16;
            f32x4 acc = {};
            #pragma unroll 4
            for (int k0 = 0; k0 < K2H; k0 += 32) {
                bf16x8 a  = *(const bf16x8*)(qp   + (long)(m0 + r) * K2H + k0 + ko);
                bf16x8 bb = *(const bf16x8*)(wqyp + (long)(n0 + r) * K2H + k0 + ko);
                acc = __builtin_amdgcn_mfma_f32_16x16x32_bf16(a, bb, acc, 0, 0, 0);
            }
            int o = n0 + r - D_;
            float bo = bd[o];
            #pragma unroll
            for (int j = 0; j < 4; ++j) {
                int b = m0 + rj + j;
                out_y[((long)b * P_ + 63) * O_ + o] = acc[j] + bo;
            }
        }
    }
}

// ---------------------------------------------------------------------------
extern "C" void kernel_launch(void* const* d_in, const int* in_sizes, int n_in,
                              void* d_out, int out_size, void* d_ws, size_t ws_size,
                              hipStream_t stream)
{
    const float* x    = (const float*)d_in[0];
    const float* V    = (const float*)d_in[1];
    const float* W    = (const float*)d_in[2];
    const float* U    = (const float*)d_in[3];
    const float* W_ih = (const float*)d_in[4];
    const float* W_hh = (const float*)d_in[5];
    const float* b_ih = (const float*)d_in[6];
    const float* b_hh = (const float*)d_in[7];
    const float* Wd   = (const float*)d_in[8];
    const float* bd   = (const float*)d_in[9];
    const float* Ws   = (const float*)d_in[10];
    const float* bs   = (const float*)d_in[11];
    const float* Wc   = (const float*)d_in[12];
    const float* bc   = (const float*)d_in[13];

    float* out_y = (float*)d_out;                         // (512,64,64)
    float* out_w = (float*)d_out + (long)B_ * P_ * O_;    // (512,64,128)

    char* p = (char*)d_ws;
    auto alloc = [&](size_t bytes) { char* r = p; p += (bytes + 255) & ~(size_t)255; return r; };
    bf16*  x_bf  = (bf16*) alloc((size_t)B_ * WIN_ * D_ * 2);
    bf16*  Uk    = (bf16*) alloc((size_t)B_ * D_ * WIN_ * 2);
    bf16*  q_buf = (bf16*) alloc((size_t)B_ * K2H * 2);
    bf16*  A0    = (bf16*) alloc((size_t)B_ * KG * 2);
    bf16*  A1    = (bf16*) alloc((size_t)B_ * KG * 2);
    float* Wq    = (float*)alloc((size_t)B_ * D_ * 4);
    float* c_f32 = (float*)alloc((size_t)B_ * H_ * 4);
    bf16*  Wqy   = (bf16*) alloc((size_t)NQY * K2H * 2);
    bf16*  Wcomb = (bf16*) alloc((size_t)2048 * KG * 2);
    bf16*  U_bf  = (bf16*) alloc((size_t)D_ * D_ * 2);
    float* bsum  = (float*)alloc((size_t)2048 * 4);
    unsigned int* bar_cnt = (unsigned int*)alloc(256);

    k_prep<<<4096, 256, 0, stream>>>(x, W, U, W_ih, W_hh, b_ih, b_hh, Wd,
                                     x_bf, Wcomb, Wqy, U_bf, bsum, A0, bar_cnt);
    k_init<<<1024, 256, 0, stream>>>(x, Ws, bs, Wc, bc, q_buf, A0, c_f32);
    k_uk<<<dim3(8, 512), 256, 0, stream>>>(U_bf, x_bf, Uk);
    k_decode<<<NBLK, 256, 0, stream>>>(x_bf, Uk, Wqy, Wcomb, V, bd, bsum,
                                       q_buf, A0, A1, Wq, c_f32, out_y, out_w, bar_cnt);
}

// Round 3
// 3903.586 us; speedup vs baseline: 2.7643x; 2.7643x over previous
//
#include <hip/hip_runtime.h>
#include <hip/hip_bf16.h>

// Problem dims
#define B_   512
#define WIN_ 128
#define D_   256
#define H_   512
#define O_   64
#define P_   64
#define K2H  1024   // 2H (q = [h|c])
#define KG   832    // gates GEMM K = O(64) + D(256) + H(512)
#define NQY  320    // packed Wq(256 rows) + Wd(64 rows, K-padded) weights

typedef __attribute__((ext_vector_type(8))) short bf16x8;
typedef __attribute__((ext_vector_type(4))) float f32x4;
using bf16 = __hip_bfloat16;

__device__ __forceinline__ float fast_tanh(float x){
    float e = __expf(2.f * x);
    return 1.f - __fdividef(2.f, e + 1.f);
}
__device__ __forceinline__ float fast_sig(float x){
    return __fdividef(1.f, 1.f + __expf(-x));
}
__device__ __forceinline__ float b_lo(unsigned int u){ return __uint_as_float(u << 16); }
__device__ __forceinline__ float b_hi(unsigned int u){ return __uint_as_float(u & 0xffff0000u); }
__device__ __forceinline__ float bs2f(short v){ return __uint_as_float(((unsigned int)(unsigned short)v) << 16); }
__device__ __forceinline__ unsigned int pack2(float a, float b){
    unsigned short sa = __builtin_bit_cast(unsigned short, __float2bfloat16(a));
    unsigned short sb = __builtin_bit_cast(unsigned short, __float2bfloat16(b));
    return (unsigned int)sa | ((unsigned int)sb << 16);
}

// ---------------- prep: dtype conversions + weight packing ----------------
__global__ void k_prep(const float* __restrict__ x, const float* __restrict__ W,
                       const float* __restrict__ U, const float* __restrict__ W_ih,
                       const float* __restrict__ W_hh, const float* __restrict__ b_ih,
                       const float* __restrict__ b_hh, const float* __restrict__ Wd,
                       bf16* __restrict__ x_bf, bf16* __restrict__ Wcomb,
                       bf16* __restrict__ Wqy, bf16* __restrict__ U_bf,
                       float* __restrict__ bsum, bf16* __restrict__ A0)
{
    const long NX  = (long)B_ * WIN_ * D_;
    const long NWC = (long)2048 * KG;
    const long NWQ = (long)NQY * K2H;
    const long NU  = (long)D_ * D_;
    const long NB  = 2048;
    const long NAY = (long)B_ * O_;
    const long total = NX + NWC + NWQ + NU + NB + NAY;
    for (long i = (long)blockIdx.x * blockDim.x + threadIdx.x; i < total;
         i += (long)gridDim.x * blockDim.x) {
        long j = i;
        if (j < NX) { x_bf[j] = __float2bfloat16(x[j]); continue; }
        j -= NX;
        if (j < NWC) {
            long n = j / KG, k = j % KG;
            float v = (k < 320) ? W_ih[n * 320 + k] : W_hh[n * 512 + (k - 320)];
            Wcomb[j] = __float2bfloat16(v); continue;
        }
        j -= NWC;
        if (j < NWQ) {
            long n = j / K2H, k = j % K2H;
            float v;
            if (n < 256) v = W[n * K2H + k];
            else { long o = n - 256; v = (k < 512) ? Wd[o * 512 + k] : 0.f; }
            Wqy[j] = __float2bfloat16(v); continue;
        }
        j -= NWQ;
        if (j < NU) { U_bf[j] = __float2bfloat16(U[j]); continue; }
        j -= NU;
        if (j < NB) { bsum[j] = b_ih[j] + b_hh[j]; continue; }
        j -= NB;
        { long b = j / O_, o = j % O_; A0[b * KG + o] = __float2bfloat16(0.f); }
    }
}

// ---------------- init: h0 = tanh(x_last@Ws^T+bs), c0 = sig(x_last@Wc^T+bc) ----
__global__ void __launch_bounds__(256) k_init(const float* __restrict__ x,
                       const float* __restrict__ Ws, const float* __restrict__ bs,
                       const float* __restrict__ Wc, const float* __restrict__ bc,
                       bf16* __restrict__ q_buf, bf16* __restrict__ A0,
                       float* __restrict__ c_f32)
{
    __shared__ __align__(16) float xl[D_];
    int b = blockIdx.x >> 1;
    int j = (blockIdx.x & 1) * 256 + threadIdx.x;
    xl[threadIdx.x] = x[(long)b * (WIN_ * D_) + 127 * D_ + threadIdx.x];
    __syncthreads();
    float hv = bs[j], cv = bc[j];
    const float* wsr = Ws + (long)j * D_;
    const float* wcr = Wc + (long)j * D_;
    #pragma unroll 4
    for (int k = 0; k < D_; k += 4) {
        float4 xa = *(const float4*)&xl[k];
        float4 wa = *(const float4*)&wsr[k];
        float4 wb = *(const float4*)&wcr[k];
        hv += xa.x*wa.x + xa.y*wa.y + xa.z*wa.z + xa.w*wa.w;
        cv += xa.x*wb.x + xa.y*wb.y + xa.z*wb.z + xa.w*wb.w;
    }
    hv = fast_tanh(hv); cv = fast_sig(cv);
    bf16 hb = __float2bfloat16(hv);
    q_buf[(long)b * K2H + j]       = hb;
    q_buf[(long)b * K2H + 512 + j] = __float2bfloat16(cv);
    A0[(long)b * KG + 320 + j]     = hb;
    c_f32[(long)b * H_ + j]        = cv;
}

// ---------------- Uk[b] = U @ x[b]^T  (x-tile staged in LDS) ----------------
__global__ void __launch_bounds__(256) k_uk(const bf16* __restrict__ U_bf,
                    const bf16* __restrict__ x_bf, bf16* __restrict__ Uk)
{
    __shared__ __align__(16) short xs[64][264];
    int b  = blockIdx.y;
    int v0 = (blockIdx.x >> 1) * 64;
    int w0 = (blockIdx.x & 1) * 64;
    {
        const short* xg = (const short*)x_bf + (long)b * (WIN_ * D_) + (long)w0 * D_;
        int row = threadIdx.x >> 2, cc = (threadIdx.x & 3) * 64;
        #pragma unroll
        for (int i = 0; i < 8; ++i)
            *(bf16x8*)(&xs[row][cc + i * 8]) = *(const bf16x8*)(xg + (long)row * D_ + cc + i * 8);
    }
    __syncthreads();
    int lane = threadIdx.x & 63;
    int wave = threadIdx.x >> 6;
    int r  = lane & 15;
    int ko = (lane >> 4) * 8;
    const short* Up = (const short*)U_bf + (long)(v0 + wave * 16 + r) * D_;
    f32x4 acc[4] = {};
    #pragma unroll 2
    for (int k0 = 0; k0 < D_; k0 += 32) {
        bf16x8 a = *(const bf16x8*)(Up + k0 + ko);
        #pragma unroll
        for (int f = 0; f < 4; ++f) {
            bf16x8 bb = *(const bf16x8*)(&xs[f * 16 + r][k0 + ko]);
            acc[f] = __builtin_amdgcn_mfma_f32_16x16x32_bf16(a, bb, acc[f], 0, 0, 0);
        }
    }
    bf16* up = Uk + (long)b * (D_ * WIN_);
    int vbase = v0 + wave * 16 + (lane >> 4) * 4;
    #pragma unroll
    for (int f = 0; f < 4; ++f) {
        int w = w0 + f * 16 + r;
        #pragma unroll
        for (int j = 0; j < 4; ++j)
            up[(long)(vbase + j) * WIN_ + w] = __float2bfloat16(acc[f][j]);
    }
}

// ---------------- step kernel 1: Wq(LDS) + y_{s-1} + attention ----------------
// 256 blocks x 512 threads; block = 2 batches; half-block per batch in attention
__global__ void __launch_bounds__(512) k_step1(
    const bf16* __restrict__ x_bf, const bf16* __restrict__ Uk,
    const bf16* __restrict__ Wqy, const float* __restrict__ V,
    const float* __restrict__ bd, const bf16* __restrict__ q_buf,
    bf16* __restrict__ A_cur, float* __restrict__ out_y,
    float* __restrict__ out_w, int s)
{
    __shared__ float q_s[2][K2H];          // unpacked [h|c] for 2 batches
    __shared__ float v_s[D_];
    __shared__ float pred[2][2][D_];       // Wq partials [kh][b][n]
    __shared__ float wq_s[2][D_];
    __shared__ float pY[4][2][O_];
    __shared__ float part[2][4][WIN_];
    __shared__ float att_s[2][WIN_];
    __shared__ float cpart[2][2][D_];
    __shared__ float redw[2][4];

    const int tid = threadIdx.x;
    const int b0  = blockIdx.x * 2;

    if (tid < D_) v_s[tid] = V[tid];
    {   // unpack q (2 x 1024 bf16) to f32 LDS
        int b  = tid >> 8;
        int k4 = (tid & 255) * 4;
        const unsigned int* qg = (const unsigned int*)q_buf + (((long)(b0 + b) * K2H + k4) >> 1);
        unsigned int u0 = qg[0], u1 = qg[1];
        q_s[b][k4 + 0] = b_lo(u0); q_s[b][k4 + 1] = b_hi(u0);
        q_s[b][k4 + 2] = b_lo(u1); q_s[b][k4 + 3] = b_hi(u1);
    }
    __syncthreads();

    {   // Wq[b][n] = sum_k W[n][k] q[b][k] ; thread = (n, k-half), both batches
        int n = tid & 255, kh = tid >> 8;
        const short* wr = (const short*)Wqy + (long)n * K2H + kh * 512;
        const float* q0 = &q_s[0][kh * 512];
        const float* q1 = &q_s[1][kh * 512];
        float s0 = 0.f, s1 = 0.f;
        #pragma unroll 4
        for (int k = 0; k < 512; k += 8) {
            bf16x8 w8 = *(const bf16x8*)(wr + k);
            #pragma unroll
            for (int i = 0; i < 8; ++i) {
                float wv = bs2f(w8[i]);
                s0 = fmaf(wv, q0[k + i], s0);
                s1 = fmaf(wv, q1[k + i], s1);
            }
        }
        pred[kh][0][n] = s0; pred[kh][1][n] = s1;
    }
    __syncthreads();
    { int b = tid >> 8, n = tid & 255; wq_s[b][n] = pred[0][b][n] + pred[1][b][n]; }

    if (s > 0) {   // y_{s-1} = Wd @ h_s + bd ; thread = (o, b, k-quarter)
        int o = tid & 63, b = (tid >> 6) & 1, kq = tid >> 7;
        const short* wdr = (const short*)Wqy + (long)(256 + o) * K2H + kq * 128;
        const float* qh = &q_s[b][kq * 128];
        float acc = 0.f;
        #pragma unroll 4
        for (int k = 0; k < 128; k += 8) {
            bf16x8 w8 = *(const bf16x8*)(wdr + k);
            #pragma unroll
            for (int i = 0; i < 8; ++i) acc = fmaf(bs2f(w8[i]), qh[k + i], acc);
        }
        pY[kq][b][o] = acc;
        __syncthreads();
        if (tid < 128) {
            int bb = tid >> 6, oo = tid & 63;
            float y = pY[0][bb][oo] + pY[1][bb][oo] + pY[2][bb][oo] + pY[3][bb][oo] + bd[oo];
            out_y[((long)(b0 + bb) * P_ + (s - 1)) * O_ + oo] = y;
            A_cur[(long)(b0 + bb) * KG + oo] = __float2bfloat16(y);
        }
    }
    __syncthreads();

    // ---------------- attention: half-block per batch ----------------
    const int tb = tid >> 8;       // batch half 0/1
    const int t2 = tid & 255;
    const int b  = b0 + tb;
    {   // score partials: thread = (w-pair, v-quarter)
        int w2 = t2 & 63, vq = t2 >> 6;
        const unsigned int* ukp =
            (const unsigned int*)(Uk + (long)b * (D_ * WIN_) + (long)vq * 64 * WIN_) + w2;
        float sc0 = 0.f, sc1 = 0.f;
        #pragma unroll 8
        for (int i = 0; i < 64; ++i) {
            unsigned int u = ukp[(long)i * 64];
            int v = vq * 64 + i;
            float wqv = wq_s[tb][v], vv = v_s[v];
            sc0 += vv * fast_tanh(wqv + b_lo(u));
            sc1 += vv * fast_tanh(wqv + b_hi(u));
        }
        part[tb][vq][w2 * 2]     = sc0;
        part[tb][vq][w2 * 2 + 1] = sc1;
    }
    __syncthreads();
    float e = 0.f, scw = 0.f;
    if (t2 < WIN_) {
        scw = part[tb][0][t2] + part[tb][1][t2] + part[tb][2][t2] + part[tb][3][t2];
        float m = scw;
        #pragma unroll
        for (int off = 32; off > 0; off >>= 1) m = fmaxf(m, __shfl_xor(m, off));
        if ((tid & 63) == 0) redw[tb][t2 >> 6] = m;
    }
    __syncthreads();
    if (t2 < WIN_) {
        float m = fmaxf(redw[tb][0], redw[tb][1]);
        e = __expf(scw - m);
        float l = e;
        #pragma unroll
        for (int off = 32; off > 0; off >>= 1) l += __shfl_xor(l, off);
        if ((tid & 63) == 0) redw[tb][2 + (t2 >> 6)] = l;
    }
    __syncthreads();
    if (t2 < WIN_) {
        float l = redw[tb][2] + redw[tb][3];
        float a = __fdividef(e, l);
        att_s[tb][t2] = a;
        out_w[((long)b * P_ + s) * WIN_ + t2] = a;
    }
    __syncthreads();
    {   // ctx: thread = (d-pair, w-half)
        int d2 = t2 & 127, wh = t2 >> 7;
        const unsigned int* xp =
            (const unsigned int*)(x_bf + (long)b * (WIN_ * D_) + (long)wh * 64 * D_) + d2;
        float c0 = 0.f, c1 = 0.f;
        #pragma unroll 8
        for (int i = 0; i < 64; ++i) {
            unsigned int u = xp[(long)i * 128];
            float a = att_s[tb][wh * 64 + i];
            c0 += a * b_lo(u);
            c1 += a * b_hi(u);
        }
        cpart[tb][wh][d2 * 2]     = c0;
        cpart[tb][wh][d2 * 2 + 1] = c1;
    }
    __syncthreads();
    if (t2 < 128) {
        int d = t2 * 2;
        float f0 = cpart[tb][0][d] + cpart[tb][1][d];
        float f1 = cpart[tb][0][d + 1] + cpart[tb][1][d + 1];
        *(unsigned int*)(A_cur + (long)b * KG + O_ + d) = pack2(f0, f1);
    }
}

// ---------------- gates GEMM + LSTM pointwise epilogue -----------------------
// grid (8,32) x 256 threads: 4 waves share B fragments via L1
__global__ void __launch_bounds__(256) k_gates(const bf16* __restrict__ A_in,
                     const bf16* __restrict__ Wcomb, const float* __restrict__ bsum,
                     float* __restrict__ c_f32, bf16* __restrict__ A_out,
                     bf16* __restrict__ q_buf)
{
    int m0 = blockIdx.x * 64 + (threadIdx.x >> 6) * 16;
    int j0 = blockIdx.y * 16;
    int lane = threadIdx.x & 63;
    int r  = lane & 15;
    int ko = (lane >> 4) * 8;
    const short* ap = (const short*)A_in;
    const short* wp = (const short*)Wcomb;
    f32x4 acc[4] = {};
    long arow = (long)(m0 + r) * KG;
    #pragma unroll 2
    for (int k0 = 0; k0 < KG; k0 += 32) {
        bf16x8 a = *(const bf16x8*)(ap + arow + k0 + ko);
        #pragma unroll
        for (int g = 0; g < 4; ++g) {
            bf16x8 bb = *(const bf16x8*)(wp + (long)(g * H_ + j0 + r) * KG + k0 + ko);
            acc[g] = __builtin_amdgcn_mfma_f32_16x16x32_bf16(a, bb, acc[g], 0, 0, 0);
        }
    }
    int jj = j0 + r;
    float bi = bsum[jj], bff = bsum[H_ + jj], bg = bsum[2*H_ + jj], bo = bsum[3*H_ + jj];
    int rj = (lane >> 4) * 4;
    #pragma unroll
    for (int j = 0; j < 4; ++j) {
        int b = m0 + rj + j;
        float iv = acc[0][j] + bi;
        float fv = acc[1][j] + bff;
        float gv = acc[2][j] + bg;
        float ov = acc[3][j] + bo;
        float c_old = c_f32[(long)b * H_ + jj];
        float cn = fast_sig(fv) * c_old + fast_sig(iv) * fast_tanh(gv);
        float hn = fast_sig(ov) * fast_tanh(cn);
        c_f32[(long)b * H_ + jj] = cn;
        bf16 hb = __float2bfloat16(hn);
        A_out[(long)b * KG + 320 + jj]  = hb;
        q_buf[(long)b * K2H + jj]       = hb;
        q_buf[(long)b * K2H + H_ + jj]  = __float2bfloat16(cn);
    }
}

// ---------------- final y (step 63) = Wd @ h_64 + bd ----------------
__global__ void __launch_bounds__(256) k_yfin(const bf16* __restrict__ q_buf,
                     const bf16* __restrict__ Wqy, const float* __restrict__ bd,
                     float* __restrict__ out_y)
{
    int b = blockIdx.x * 4 + (threadIdx.x >> 6);
    int o = threadIdx.x & 63;
    const short* wdr = (const short*)Wqy + (long)(256 + o) * K2H;
    const short* qh  = (const short*)q_buf + (long)b * K2H;
    float acc = bd[o];
    #pragma unroll 4
    for (int k = 0; k < 512; k += 8) {
        bf16x8 w8 = *(const bf16x8*)(wdr + k);
        bf16x8 h8 = *(const bf16x8*)(qh + k);
        #pragma unroll
        for (int i = 0; i < 8; ++i) acc = fmaf(bs2f(w8[i]), bs2f(h8[i]), acc);
    }
    out_y[((long)b * P_ + 63) * O_ + o] = acc;
}

// ---------------------------------------------------------------------------
extern "C" void kernel_launch(void* const* d_in, const int* in_sizes, int n_in,
                              void* d_out, int out_size, void* d_ws, size_t ws_size,
                              hipStream_t stream)
{
    const float* x    = (const float*)d_in[0];
    const float* V    = (const float*)d_in[1];
    const float* W    = (const float*)d_in[2];
    const float* U    = (const float*)d_in[3];
    const float* W_ih = (const float*)d_in[4];
    const float* W_hh = (const float*)d_in[5];
    const float* b_ih = (const float*)d_in[6];
    const float* b_hh = (const float*)d_in[7];
    const float* Wd   = (const float*)d_in[8];
    const float* bd   = (const float*)d_in[9];
    const float* Ws   = (const float*)d_in[10];
    const float* bs   = (const float*)d_in[11];
    const float* Wc   = (const float*)d_in[12];
    const float* bc   = (const float*)d_in[13];

    float* out_y = (float*)d_out;                         // (512,64,64)
    float* out_w = (float*)d_out + (long)B_ * P_ * O_;    // (512,64,128)

    char* p = (char*)d_ws;
    auto alloc = [&](size_t bytes) { char* r = p; p += (bytes + 255) & ~(size_t)255; return r; };
    bf16*  x_bf  = (bf16*) alloc((size_t)B_ * WIN_ * D_ * 2);
    bf16*  Uk    = (bf16*) alloc((size_t)B_ * D_ * WIN_ * 2);
    bf16*  q_buf = (bf16*) alloc((size_t)B_ * K2H * 2);
    bf16*  A0    = (bf16*) alloc((size_t)B_ * KG * 2);
    bf16*  A1    = (bf16*) alloc((size_t)B_ * KG * 2);
    float* c_f32 = (float*)alloc((size_t)B_ * H_ * 4);
    bf16*  Wqy   = (bf16*) alloc((size_t)NQY * K2H * 2);
    bf16*  Wcomb = (bf16*) alloc((size_t)2048 * KG * 2);
    bf16*  U_bf  = (bf16*) alloc((size_t)D_ * D_ * 2);
    float* bsum  = (float*)alloc((size_t)2048 * 4);
    bf16*  Abuf[2] = { A0, A1 };

    k_prep<<<4096, 256, 0, stream>>>(x, W, U, W_ih, W_hh, b_ih, b_hh, Wd,
                                     x_bf, Wcomb, Wqy, U_bf, bsum, A0);
    k_init<<<1024, 256, 0, stream>>>(x, Ws, bs, Wc, bc, q_buf, A0, c_f32);
    k_uk<<<dim3(8, 512), 256, 0, stream>>>(U_bf, x_bf, Uk);

    for (int s = 0; s < P_; ++s) {
        k_step1<<<256, 512, 0, stream>>>(x_bf, Uk, Wqy, V, bd, q_buf,
                                         Abuf[s & 1], out_y, out_w, s);
        k_gates<<<dim3(8, 32), 256, 0, stream>>>(Abuf[s & 1], Wcomb, bsum,
                                                 c_f32, Abuf[(s + 1) & 1], q_buf);
    }
    k_yfin<<<128, 256, 0, stream>>>(q_buf, Wqy, bd, out_y);
}

// Round 4
// 2930.198 us; speedup vs baseline: 3.6826x; 1.3322x over previous
//
#include <hip/hip_runtime.h>
#include <hip/hip_bf16.h>

// Problem dims
#define B_   512
#define WIN_ 128
#define D_   256
#define H_   512
#define O_   64
#define P_   64
#define K2H  1024   // 2H (q = [h|c])
#define KG   832    // gates GEMM K = O(64) + D(256) + H(512)
#define NQY  320    // packed Wq(256 rows) + Wd(64 rows, K-padded) weights

typedef __attribute__((ext_vector_type(8))) short bf16x8;
typedef __attribute__((ext_vector_type(4))) float f32x4;
using bf16 = __hip_bfloat16;

__device__ __forceinline__ float fast_tanh(float x){
    float e = __expf(2.f * x);
    return 1.f - __fdividef(2.f, e + 1.f);
}
__device__ __forceinline__ float fast_sig(float x){
    return __fdividef(1.f, 1.f + __expf(-x));
}
__device__ __forceinline__ float b_lo(unsigned int u){ return __uint_as_float(u << 16); }
__device__ __forceinline__ float b_hi(unsigned int u){ return __uint_as_float(u & 0xffff0000u); }
__device__ __forceinline__ unsigned int pack2(float a, float b){
    unsigned short sa = __builtin_bit_cast(unsigned short, __float2bfloat16(a));
    unsigned short sb = __builtin_bit_cast(unsigned short, __float2bfloat16(b));
    return (unsigned int)sa | ((unsigned int)sb << 16);
}

// ---------------- prep: dtype conversions + weight packing ----------------
__global__ void k_prep(const float* __restrict__ x, const float* __restrict__ W,
                       const float* __restrict__ U, const float* __restrict__ W_ih,
                       const float* __restrict__ W_hh, const float* __restrict__ b_ih,
                       const float* __restrict__ b_hh, const float* __restrict__ Wd,
                       const float* __restrict__ Ws, const float* __restrict__ Wc,
                       bf16* __restrict__ x_bf, bf16* __restrict__ Wcomb,
                       bf16* __restrict__ Wqy, bf16* __restrict__ U_bf,
                       bf16* __restrict__ Wsc, float* __restrict__ bsum,
                       bf16* __restrict__ A0)
{
    const long NX  = (long)B_ * WIN_ * D_;        // x -> bf16
    const long NWC = (long)2048 * KG;             // [W_ih|W_hh]
    const long NWQ = (long)NQY * K2H;             // [W ; Wd(K-pad)]
    const long NU  = (long)D_ * D_;               // U
    const long NWS = (long)K2H * D_;              // [Ws;Wc]
    const long NB  = 2048;
    const long NAY = (long)B_ * O_;               // zero y-slot of A0
    const long total = NX + NWC + NWQ + NU + NWS + NB + NAY;
    for (long i = (long)blockIdx.x * blockDim.x + threadIdx.x; i < total;
         i += (long)gridDim.x * blockDim.x) {
        long j = i;
        if (j < NX) { x_bf[j] = __float2bfloat16(x[j]); continue; }
        j -= NX;
        if (j < NWC) {
            long n = j / KG, k = j % KG;
            float v = (k < 320) ? W_ih[n * 320 + k] : W_hh[n * 512 + (k - 320)];
            Wcomb[j] = __float2bfloat16(v); continue;
        }
        j -= NWC;
        if (j < NWQ) {
            long n = j / K2H, k = j % K2H;
            float v;
            if (n < 256) v = W[n * K2H + k];
            else { long o = n - 256; v = (k < 512) ? Wd[o * 512 + k] : 0.f; }
            Wqy[j] = __float2bfloat16(v); continue;
        }
        j -= NWQ;
        if (j < NU) { U_bf[j] = __float2bfloat16(U[j]); continue; }
        j -= NU;
        if (j < NWS) {
            long n = j / D_, k = j % D_;
            float v = (n < 512) ? Ws[n * D_ + k] : Wc[(n - 512) * D_ + k];
            Wsc[j] = __float2bfloat16(v); continue;
        }
        j -= NWS;
        if (j < NB) { bsum[j] = b_ih[j] + b_hh[j]; continue; }
        j -= NB;
        { long b = j / O_, o = j % O_; A0[b * KG + o] = __float2bfloat16(0.f); }
    }
}

// ------- init (MFMA): x_last(512x256) @ Wsc^T(1024x256) -> h0 | c0 ---------
__global__ void __launch_bounds__(256) k_init2(const bf16* __restrict__ x_bf,
                       const bf16* __restrict__ Wsc, const float* __restrict__ bs,
                       const float* __restrict__ bc, bf16* __restrict__ q_buf,
                       bf16* __restrict__ A0, float* __restrict__ c_f32)
{
    int wave = threadIdx.x >> 6, lane = threadIdx.x & 63;
    int m0 = blockIdx.x * 16;                 // batch tile
    int n0 = blockIdx.y * 64 + wave * 16;     // output-dim tile (0..1023)
    int r = lane & 15, ko = (lane >> 4) * 8, rj = (lane >> 4) * 4;
    const short* xp = (const short*)x_bf;
    const short* wp = (const short*)Wsc;
    f32x4 acc = {};
    #pragma unroll
    for (int k0 = 0; k0 < D_; k0 += 32) {
        bf16x8 a  = *(const bf16x8*)(xp + (long)(m0 + r) * (WIN_ * D_) + 127 * D_ + k0 + ko);
        bf16x8 bb = *(const bf16x8*)(wp + (long)(n0 + r) * D_ + k0 + ko);
        acc = __builtin_amdgcn_mfma_f32_16x16x32_bf16(a, bb, acc, 0, 0, 0);
    }
    int n = n0 + r;
    if (n0 < 512) {          // h0 = tanh(. + bs)
        float bias = bs[n];
        #pragma unroll
        for (int j = 0; j < 4; ++j) {
            int b = m0 + rj + j;
            float hv = fast_tanh(acc[j] + bias);
            bf16 hb = __float2bfloat16(hv);
            q_buf[(long)b * K2H + n]    = hb;
            A0[(long)b * KG + 320 + n]  = hb;
        }
    } else {                 // c0 = sigmoid(. + bc)
        float bias = bc[n - 512];
        #pragma unroll
        for (int j = 0; j < 4; ++j) {
            int b = m0 + rj + j;
            float cv = fast_sig(acc[j] + bias);
            q_buf[(long)b * K2H + n]        = __float2bfloat16(cv);
            c_f32[(long)b * H_ + (n - 512)] = cv;
        }
    }
}

// ---------------- Uk[b] = U @ x[b]^T  (x-tile staged in LDS) ----------------
__global__ void __launch_bounds__(256) k_uk(const bf16* __restrict__ U_bf,
                    const bf16* __restrict__ x_bf, bf16* __restrict__ Uk)
{
    __shared__ __align__(16) short xs[64][264];
    int b  = blockIdx.y;
    int v0 = (blockIdx.x >> 1) * 64;
    int w0 = (blockIdx.x & 1) * 64;
    {
        const short* xg = (const short*)x_bf + (long)b * (WIN_ * D_) + (long)w0 * D_;
        int row = threadIdx.x >> 2, cc = (threadIdx.x & 3) * 64;
        #pragma unroll
        for (int i = 0; i < 8; ++i)
            *(bf16x8*)(&xs[row][cc + i * 8]) = *(const bf16x8*)(xg + (long)row * D_ + cc + i * 8);
    }
    __syncthreads();
    int lane = threadIdx.x & 63;
    int wave = threadIdx.x >> 6;
    int r  = lane & 15;
    int ko = (lane >> 4) * 8;
    const short* Up = (const short*)U_bf + (long)(v0 + wave * 16 + r) * D_;
    f32x4 acc[4] = {};
    #pragma unroll 2
    for (int k0 = 0; k0 < D_; k0 += 32) {
        bf16x8 a = *(const bf16x8*)(Up + k0 + ko);
        #pragma unroll
        for (int f = 0; f < 4; ++f) {
            bf16x8 bb = *(const bf16x8*)(&xs[f * 16 + r][k0 + ko]);
            acc[f] = __builtin_amdgcn_mfma_f32_16x16x32_bf16(a, bb, acc[f], 0, 0, 0);
        }
    }
    bf16* up = Uk + (long)b * (D_ * WIN_);
    int vbase = v0 + wave * 16 + (lane >> 4) * 4;
    #pragma unroll
    for (int f = 0; f < 4; ++f) {
        int w = w0 + f * 16 + r;
        #pragma unroll
        for (int j = 0; j < 4; ++j)
            up[(long)(vbase + j) * WIN_ + w] = __float2bfloat16(acc[f][j]);
    }
}

// ---------------- fused Wq + y GEMM: q(512x1024) @ Wqy^T(320x1024) -----------
__global__ void __launch_bounds__(64) k_wqy(const bf16* __restrict__ q_buf,
                     const bf16* __restrict__ Wqy, const float* __restrict__ bd,
                     float* __restrict__ Wq, float* __restrict__ out_y,
                     bf16* __restrict__ A_buf, int ystep)
{
    int m0 = blockIdx.x * 16;
    int n0 = blockIdx.y * 32;
    int lane = threadIdx.x & 63;
    int r  = lane & 15;
    int ko = (lane >> 4) * 8;
    const short* qp = (const short*)q_buf;
    const short* wp = (const short*)Wqy;
    f32x4 acc[2] = {};
    for (int k0 = 0; k0 < K2H; k0 += 32) {
        bf16x8 a = *(const bf16x8*)(qp + (long)(m0 + r) * K2H + k0 + ko);
        #pragma unroll
        for (int f = 0; f < 2; ++f) {
            bf16x8 bb = *(const bf16x8*)(wp + (long)(n0 + f*16 + r) * K2H + k0 + ko);
            acc[f] = __builtin_amdgcn_mfma_f32_16x16x32_bf16(a, bb, acc[f], 0, 0, 0);
        }
    }
    #pragma unroll
    for (int f = 0; f < 2; ++f) {
        int n = n0 + f * 16 + r;
        #pragma unroll
        for (int j = 0; j < 4; ++j) {
            int b = m0 + (lane >> 4) * 4 + j;
            float val = acc[f][j];
            if (n < 256) {
                Wq[(long)b * D_ + n] = val;
            } else if (ystep >= 0) {
                int o = n - 256;
                val += bd[o];
                out_y[((long)b * P_ + ystep) * O_ + o] = val;
                A_buf[(long)b * KG + o] = __float2bfloat16(val);
            }
        }
    }
}

// ---------------- attention: 2 batches per 512-thread block ----------------
__global__ void __launch_bounds__(512) k_att(
    const bf16* __restrict__ x_bf, const bf16* __restrict__ Uk,
    const float* __restrict__ Wq, const float* __restrict__ V,
    bf16* __restrict__ A_cur, float* __restrict__ out_w, int s)
{
    __shared__ float v_s[D_];
    __shared__ float wq_s[2][D_];
    __shared__ float part[2][4][WIN_];
    __shared__ float att_s[2][WIN_];
    __shared__ float cpart[2][2][D_];
    __shared__ float redw[2][4];

    const int tid = threadIdx.x;
    const int b0  = blockIdx.x * 2;
    const int tb  = tid >> 8;        // batch half 0/1
    const int t2  = tid & 255;

    if (tid < D_) v_s[tid] = V[tid];
    { int bb = tid >> 8, n = tid & 255; wq_s[bb][n] = Wq[(long)(b0 + bb) * D_ + n]; }
    __syncthreads();

    const int b = b0 + tb;
    {   // score partials: thread = (w-pair, v-quarter)
        int w2 = t2 & 63, vq = t2 >> 6;
        const unsigned int* ukp =
            (const unsigned int*)(Uk + (long)b * (D_ * WIN_) + (long)vq * 64 * WIN_) + w2;
        float sc0 = 0.f, sc1 = 0.f;
        #pragma unroll 8
        for (int i = 0; i < 64; ++i) {
            unsigned int u = ukp[(long)i * 64];
            int v = vq * 64 + i;
            float wqv = wq_s[tb][v], vv = v_s[v];
            sc0 += vv * fast_tanh(wqv + b_lo(u));
            sc1 += vv * fast_tanh(wqv + b_hi(u));
        }
        part[tb][vq][w2 * 2]     = sc0;
        part[tb][vq][w2 * 2 + 1] = sc1;
    }
    __syncthreads();
    float e = 0.f, scw = 0.f;
    if (t2 < WIN_) {
        scw = part[tb][0][t2] + part[tb][1][t2] + part[tb][2][t2] + part[tb][3][t2];
        float m = scw;
        #pragma unroll
        for (int off = 32; off > 0; off >>= 1) m = fmaxf(m, __shfl_xor(m, off));
        if ((tid & 63) == 0) redw[tb][t2 >> 6] = m;
    }
    __syncthreads();
    if (t2 < WIN_) {
        float m = fmaxf(redw[tb][0], redw[tb][1]);
        e = __expf(scw - m);
        float l = e;
        #pragma unroll
        for (int off = 32; off > 0; off >>= 1) l += __shfl_xor(l, off);
        if ((tid & 63) == 0) redw[tb][2 + (t2 >> 6)] = l;
    }
    __syncthreads();
    if (t2 < WIN_) {
        float l = redw[tb][2] + redw[tb][3];
        float a = __fdividef(e, l);
        att_s[tb][t2] = a;
        out_w[((long)b * P_ + s) * WIN_ + t2] = a;
    }
    __syncthreads();
    {   // ctx: thread = (d-pair, w-half)
        int d2 = t2 & 127, wh = t2 >> 7;
        const unsigned int* xp =
            (const unsigned int*)(x_bf + (long)b * (WIN_ * D_) + (long)wh * 64 * D_) + d2;
        float c0 = 0.f, c1 = 0.f;
        #pragma unroll 8
        for (int i = 0; i < 64; ++i) {
            unsigned int u = xp[(long)i * 128];
            float a = att_s[tb][wh * 64 + i];
            c0 += a * b_lo(u);
            c1 += a * b_hi(u);
        }
        cpart[tb][wh][d2 * 2]     = c0;
        cpart[tb][wh][d2 * 2 + 1] = c1;
    }
    __syncthreads();
    if (t2 < 128) {
        int d = t2 * 2;
        float f0 = cpart[tb][0][d] + cpart[tb][1][d];
        float f1 = cpart[tb][0][d + 1] + cpart[tb][1][d + 1];
        *(unsigned int*)(A_cur + (long)b * KG + O_ + d) = pack2(f0, f1);
    }
}

// ---------------- gates GEMM + LSTM pointwise epilogue -----------------------
__global__ void __launch_bounds__(256) k_gates(const bf16* __restrict__ A_in,
                     const bf16* __restrict__ Wcomb, const float* __restrict__ bsum,
                     float* __restrict__ c_f32, bf16* __restrict__ A_out,
                     bf16* __restrict__ q_buf)
{
    int m0 = blockIdx.x * 64 + (threadIdx.x >> 6) * 16;
    int j0 = blockIdx.y * 16;
    int lane = threadIdx.x & 63;
    int r  = lane & 15;
    int ko = (lane >> 4) * 8;
    const short* ap = (const short*)A_in;
    const short* wp = (const short*)Wcomb;
    f32x4 acc[4] = {};
    long arow = (long)(m0 + r) * KG;
    #pragma unroll 2
    for (int k0 = 0; k0 < KG; k0 += 32) {
        bf16x8 a = *(const bf16x8*)(ap + arow + k0 + ko);
        #pragma unroll
        for (int g = 0; g < 4; ++g) {
            bf16x8 bb = *(const bf16x8*)(wp + (long)(g * H_ + j0 + r) * KG + k0 + ko);
            acc[g] = __builtin_amdgcn_mfma_f32_16x16x32_bf16(a, bb, acc[g], 0, 0, 0);
        }
    }
    int jj = j0 + r;
    float bi = bsum[jj], bff = bsum[H_ + jj], bg = bsum[2*H_ + jj], bo = bsum[3*H_ + jj];
    int rj = (lane >> 4) * 4;
    #pragma unroll
    for (int j = 0; j < 4; ++j) {
        int b = m0 + rj + j;
        float iv = acc[0][j] + bi;
        float fv = acc[1][j] + bff;
        float gv = acc[2][j] + bg;
        float ov = acc[3][j] + bo;
        float c_old = c_f32[(long)b * H_ + jj];
        float cn = fast_sig(fv) * c_old + fast_sig(iv) * fast_tanh(gv);
        float hn = fast_sig(ov) * fast_tanh(cn);
        c_f32[(long)b * H_ + jj] = cn;
        bf16 hb = __float2bfloat16(hn);
        A_out[(long)b * KG + 320 + jj]  = hb;
        q_buf[(long)b * K2H + jj]       = hb;
        q_buf[(long)b * K2H + H_ + jj]  = __float2bfloat16(cn);
    }
}

// ---------------- final y (step 63) = Wd @ h_64 + bd ----------------
__global__ void __launch_bounds__(256) k_yfin(const bf16* __restrict__ q_buf,
                     const bf16* __restrict__ Wqy, const float* __restrict__ bd,
                     float* __restrict__ out_y)
{
    int b = blockIdx.x * 4 + (threadIdx.x >> 6);
    int o = threadIdx.x & 63;
    const short* wdr = (const short*)Wqy + (long)(256 + o) * K2H;
    const short* qh  = (const short*)q_buf + (long)b * K2H;
    float acc = bd[o];
    #pragma unroll 4
    for (int k = 0; k < 512; k += 8) {
        bf16x8 w8 = *(const bf16x8*)(wdr + k);
        bf16x8 h8 = *(const bf16x8*)(qh + k);
        #pragma unroll
        for (int i = 0; i < 8; ++i)
            acc = fmaf(__uint_as_float(((unsigned int)(unsigned short)w8[i]) << 16),
                       __uint_as_float(((unsigned int)(unsigned short)h8[i]) << 16), acc);
    }
    out_y[((long)b * P_ + 63) * O_ + o] = acc;
}

// ---------------------------------------------------------------------------
extern "C" void kernel_launch(void* const* d_in, const int* in_sizes, int n_in,
                              void* d_out, int out_size, void* d_ws, size_t ws_size,
                              hipStream_t stream)
{
    const float* x    = (const float*)d_in[0];
    const float* V    = (const float*)d_in[1];
    const float* W    = (const float*)d_in[2];
    const float* U    = (const float*)d_in[3];
    const float* W_ih = (const float*)d_in[4];
    const float* W_hh = (const float*)d_in[5];
    const float* b_ih = (const float*)d_in[6];
    const float* b_hh = (const float*)d_in[7];
    const float* Wd   = (const float*)d_in[8];
    const float* bd   = (const float*)d_in[9];
    const float* Ws   = (const float*)d_in[10];
    const float* bs   = (const float*)d_in[11];
    const float* Wc   = (const float*)d_in[12];
    const float* bc   = (const float*)d_in[13];

    float* out_y = (float*)d_out;                         // (512,64,64)
    float* out_w = (float*)d_out + (long)B_ * P_ * O_;    // (512,64,128)

    char* p = (char*)d_ws;
    auto alloc = [&](size_t bytes) { char* r = p; p += (bytes + 255) & ~(size_t)255; return r; };
    bf16*  x_bf  = (bf16*) alloc((size_t)B_ * WIN_ * D_ * 2);
    bf16*  Uk    = (bf16*) alloc((size_t)B_ * D_ * WIN_ * 2);
    bf16*  q_buf = (bf16*) alloc((size_t)B_ * K2H * 2);
    bf16*  A0    = (bf16*) alloc((size_t)B_ * KG * 2);
    bf16*  A1    = (bf16*) alloc((size_t)B_ * KG * 2);
    float* Wq    = (float*)alloc((size_t)B_ * D_ * 4);
    float* c_f32 = (float*)alloc((size_t)B_ * H_ * 4);
    bf16*  Wqy   = (bf16*) alloc((size_t)NQY * K2H * 2);
    bf16*  Wcomb = (bf16*) alloc((size_t)2048 * KG * 2);
    bf16*  U_bf  = (bf16*) alloc((size_t)D_ * D_ * 2);
    bf16*  Wsc   = (bf16*) alloc((size_t)K2H * D_ * 2);
    float* bsum  = (float*)alloc((size_t)2048 * 4);
    bf16*  Abuf[2] = { A0, A1 };

    k_prep<<<4096, 256, 0, stream>>>(x, W, U, W_ih, W_hh, b_ih, b_hh, Wd, Ws, Wc,
                                     x_bf, Wcomb, Wqy, U_bf, Wsc, bsum, A0);
    k_init2<<<dim3(32, 16), 256, 0, stream>>>(x_bf, Wsc, bs, bc, q_buf, A0, c_f32);
    k_uk<<<dim3(8, 512), 256, 0, stream>>>(U_bf, x_bf, Uk);

    for (int s = 0; s < P_; ++s) {
        k_wqy<<<dim3(32, 10), 64, 0, stream>>>(q_buf, Wqy, bd, Wq, out_y,
                                               Abuf[s & 1], s - 1);
        k_att<<<256, 512, 0, stream>>>(x_bf, Uk, Wq, V, Abuf[s & 1], out_w, s);
        k_gates<<<dim3(8, 32), 256, 0, stream>>>(Abuf[s & 1], Wcomb, bsum,
                                                 c_f32, Abuf[(s + 1) & 1], q_buf);
    }
    k_yfin<<<128, 256, 0, stream>>>(q_buf, Wqy, bd, out_y);
}